// Round 16
// baseline (218.630 us; speedup 1.0000x reference)
//
#include <hip/hip_runtime.h>
#include <cstddef>

// ---------------------------------------------------------------------------
// 2-layer GAT forward, CSR-gather formulation.
// R16: (a) no hipMemsetAsync — k_bhist writes per-block partial histograms
// (plain stores, no pre-zero, no global atomics), k_bscan reduces+scans;
// (b) k_embed_proj1 prefetches next iteration's emb row into registers so
// the ds_write's vmcnt wait is hidden under the current 128-FMA loop.
// Rest identical to R15. Requires n < 65536.
// ---------------------------------------------------------------------------

#define EPB 2048   // edges per k_part block
#define NHB 64     // histogram partial blocks

typedef float f32x2 __attribute__((ext_vector_type(2)));

__device__ __forceinline__ float lrelu(float x) { return x > 0.f ? x : 0.2f * x; }
__device__ __forceinline__ int iadd(int* p, int v) {
  return __hip_atomic_fetch_add(p, v, __ATOMIC_RELAXED, __HIP_MEMORY_SCOPE_AGENT);
}
__device__ __forceinline__ unsigned f2bf(float f) {         // RNE float->bf16
  unsigned int u = __float_as_uint(f);
  u += 0x7FFFu + ((u >> 16) & 1u);
  return u >> 16;
}

// ---- CSR build ------------------------------------------------------------

// per-block partial histograms; every slot written -> no pre-zeroing needed
__global__ __launch_bounds__(256) void k_bhist(
    const int* __restrict__ ei, int* __restrict__ bhistP, int E)
{
  __shared__ int h[256];
  h[threadIdx.x] = 0; __syncthreads();
  for (int e = blockIdx.x * 256 + threadIdx.x; e < E; e += NHB * 256)
    atomicAdd(&h[__builtin_nontemporal_load(&ei[E + e]) >> 8], 1);
  __syncthreads();
  bhistP[(blockIdx.x << 8) + threadIdx.x] = h[threadIdx.x];
}

// reduce partials + scan bucket sizes -> bufOffs[0..nb], tails
__global__ __launch_bounds__(256) void k_bscan(
    const int* __restrict__ bhistP, int* __restrict__ bufOffs,
    int* __restrict__ tail, int nb)
{
  __shared__ int sp[256];
  const int tid = threadIdx.x;
  int v = 0;
#pragma unroll 8
  for (int b = 0; b < NHB; ++b) v += bhistP[(b << 8) + tid];
  sp[tid] = v; __syncthreads();
  for (int off = 1; off < 256; off <<= 1) {
    int t = (tid >= off) ? sp[tid - off] : 0;
    __syncthreads();
    sp[tid] += t;
    __syncthreads();
  }
  int excl = sp[tid] - v;
  if (tid < nb) { bufOffs[tid] = excl; tail[tid] = excl; }
  if (tid == 255) bufOffs[nb] = sp[255];
}

__global__ __launch_bounds__(256) void k_part(
    const int* __restrict__ ei, int* __restrict__ tail,
    int* __restrict__ buf, int E)
{
  __shared__ int sPair[EPB];
  __shared__ unsigned char sKey[EPB];
  __shared__ int sHist[256];
  __shared__ int sBase[256];
  const int tid = threadIdx.x;
  sHist[tid] = 0; __syncthreads();
  const int e0 = blockIdx.x * EPB;
  int m = E - e0; if (m > EPB) m = EPB;
  for (int i = tid; i < m; i += 256) {
    int d = __builtin_nontemporal_load(&ei[E + e0 + i]);
    int s = __builtin_nontemporal_load(&ei[e0 + i]);
    sPair[i] = ((d & 255) << 16) | s;
    int b = d >> 8;
    sKey[i] = (unsigned char)b;
    atomicAdd(&sHist[b], 1);
  }
  __syncthreads();
  int c = sHist[tid];
  sBase[tid] = c ? iadd(&tail[tid], c) : 0;
  sHist[tid] = 0;
  __syncthreads();
  for (int i = tid; i < m; i += 256) {
    int b = sKey[i];
    int off = atomicAdd(&sHist[b], 1);
    buf[sBase[b] + off] = sPair[i];
  }
}

// per-bucket: LDS hist (incl. self-loop) + scan -> offs, then LDS-cursor
// scatter into csr. csr holds src<<6 (pre-scaled byte offset for 64B rows).
__global__ __launch_bounds__(256) void k_coffs_scat(
    const int* __restrict__ buf, const int* __restrict__ bufOffs,
    int* __restrict__ offs, int* __restrict__ csr, int n)
{
  __shared__ int h[256];
  __shared__ int cur[256];
  const int b = blockIdx.x, tid = threadIdx.x;
  const int d = (b << 8) + tid;
  h[tid] = (d < n) ? 1 : 0;
  __syncthreads();
  const int lo = bufOffs[b], hi = bufOffs[b + 1];
  for (int i = lo + tid; i < hi; i += 256)
    atomicAdd(&h[(buf[i] >> 16) & 255], 1);
  __syncthreads();
  const int cnt = h[tid];
  for (int off = 1; off < 256; off <<= 1) {
    int t = (tid >= off) ? h[tid - off] : 0;
    __syncthreads();
    h[tid] += t;
    __syncthreads();
  }
  const int excl = h[tid] - cnt;
  const int base = lo + (b << 8);
  if (d < n) {
    const int o = base + excl;
    offs[d] = o;
    csr[o] = d << 6;                    // self-loop first
    cur[tid] = o + 1;
    if (d == n - 1) offs[n] = o + cnt;
  }
  __syncthreads();
  for (int i = lo + tid; i < hi; i += 256) {
    int p = buf[i];
    int pos = atomicAdd(&cur[(p >> 16) & 255], 1);
    csr[pos] = (p & 0xFFFF) << 6;
  }
}

// ---- K1: embedding gather + x@W1 (128->64). Barrier-free, prefetched. -----
__global__ __launch_bounds__(256) void k_embed_proj1(
    const int* __restrict__ x_ids, const float* __restrict__ emb,
    const float* __restrict__ W1, const float* __restrict__ a_dst1,
    unsigned char* __restrict__ xp1f8, float* __restrict__ adst1, int n)
{
  __shared__ float sWT[64 * 132];          // transposed W1, pad 132 (16B align)
  __shared__ float sx[4][2][128];          // per-wave slot [wid][node][k]
  for (int i = threadIdx.x; i < 128 * 64; i += 256) {
    int k = i >> 6, c = i & 63;
    sWT[c * 132 + k] = W1[i];
  }
  __syncthreads();                         // the ONLY block barrier
  const int wid = threadIdx.x >> 6;
  const int ln  = threadIdx.x & 63;
  const int ch  = ln;
  const int hh = ch >> 3, cc = ch & 7;
  const float ad = a_dst1[ch];
  const float* wrow = sWT + ch * 132;
  const int half = ln >> 5;
  const int qk   = ln & 31;
  float* myx = &sx[wid][0][0];
  // prefetch g=0 row
  float4 xv = make_float4(0.f, 0.f, 0.f, 0.f);
  {
    const int node_s = blockIdx.x * 32 + wid * 2 + half;
    if (node_s < n)
      xv = *(const float4*)(emb + (size_t)x_ids[node_s] * 128 + qk * 4);
  }
  for (int g = 0; g < 4; ++g) {
    *(float4*)(myx + half * 128 + qk * 4) = xv;   // vmcnt wait hidden (issued last iter)
    // issue next-iteration load before computing
    float4 xnext = make_float4(0.f, 0.f, 0.f, 0.f);
    if (g < 3) {
      const int node_s = blockIdx.x * 32 + (g + 1) * 8 + wid * 2 + half;
      if (node_s < n)
        xnext = *(const float4*)(emb + (size_t)x_ids[node_s] * 128 + qk * 4);
    }
    asm volatile("s_waitcnt lgkmcnt(0)" ::: "memory");  // ds_write visible in-wave
    const int node0 = blockIdx.x * 32 + g * 8 + wid * 2;
    float acc0 = 0.f, acc1 = 0.f;
#pragma unroll 8
    for (int k = 0; k < 128; k += 4) {
      const float4 wv = *(const float4*)(wrow + k);
      const float4 x0 = *(const float4*)(myx + k);
      const float4 x1 = *(const float4*)(myx + 128 + k);
      acc0 = fmaf(x0.x, wv.x, acc0); acc1 = fmaf(x1.x, wv.x, acc1);
      acc0 = fmaf(x0.y, wv.y, acc0); acc1 = fmaf(x1.y, wv.y, acc1);
      acc0 = fmaf(x0.z, wv.z, acc0); acc1 = fmaf(x1.z, wv.z, acc1);
      acc0 = fmaf(x0.w, wv.w, acc0); acc1 = fmaf(x1.w, wv.w, acc1);
    }
    float vd0 = acc0 * ad, vd1 = acc1 * ad;
    vd0 += __shfl_xor(vd0, 1); vd0 += __shfl_xor(vd0, 2); vd0 += __shfl_xor(vd0, 4);
    vd1 += __shfl_xor(vd1, 1); vd1 += __shfl_xor(vd1, 2); vd1 += __shfl_xor(vd1, 4);
    const int node1 = node0 + 1;
    if (node0 < n) {
      unsigned int pk = (unsigned int)__builtin_amdgcn_cvt_pk_fp8_f32(
          acc0 * 16.f, acc0 * 16.f, 0, false);
      xp1f8[(size_t)node0 * 64 + ch] = (unsigned char)pk;
      if (cc == 0) adst1[node0 * 8 + hh] = vd0;
    }
    if (node1 < n) {
      unsigned int pk = (unsigned int)__builtin_amdgcn_cvt_pk_fp8_f32(
          acc1 * 16.f, acc1 * 16.f, 0, false);
      xp1f8[(size_t)node1 * 64 + ch] = (unsigned char)pk;
      if (cc == 0) adst1[node1 * 8 + hh] = vd1;
    }
    asm volatile("s_waitcnt lgkmcnt(0)" ::: "memory");  // reads done before next write
    xv = xnext;
  }
}

// ---- G1: pure layer-1 gather. No LDS, no barrier, 4 independent waves. ----
__global__ __launch_bounds__(256) void k_gather1(
    const int* __restrict__ offs, const int* __restrict__ csr,
    const float* __restrict__ a_src1, const float* __restrict__ adst1,
    const unsigned char* __restrict__ xp1f8,
    unsigned char* __restrict__ xp1h, int n)
{
  const int wid = threadIdx.x >> 6;
  const int ln  = threadIdx.x & 63;
  const int eslot = ln >> 3;
  const int h     = ln & 7;
  const int c0    = h << 3;
  const int d = blockIdx.x * 4 + wid;
  if (d >= n) return;
  const float4 a1lo0 = *(const float4*)(a_src1 + c0);
  const float4 a1hi0 = *(const float4*)(a_src1 + c0 + 4);
  const float s0 = a1lo0.x * 0.0625f, s1 = a1lo0.y * 0.0625f;
  const float s2 = a1lo0.z * 0.0625f, s3 = a1lo0.w * 0.0625f;
  const float s4 = a1hi0.x * 0.0625f, s5 = a1hi0.y * 0.0625f;
  const float s6 = a1hi0.z * 0.0625f, s7 = a1hi0.w * 0.0625f;
  const int beg = offs[d], end = offs[d + 1];
  const float adT = adst1[(size_t)d * 8 + h];
  const int hoff = h << 3;
  float a0=0.f,a1=0.f,a2=0.f,a3=0.f,a4=0.f,a5=0.f,a6=0.f,a7=0.f,den=0.f;
#pragma unroll 4
  for (int jb = beg + eslot; jb < end; jb += 8) {
    const int sv = __builtin_nontemporal_load(&csr[jb]);   // src<<6
    const uint2 u = *(const uint2*)(xp1f8 + (unsigned)sv + hoff);
    const f32x2 v01 = __builtin_amdgcn_cvt_pk_f32_fp8((int)u.x, false);
    const f32x2 v23 = __builtin_amdgcn_cvt_pk_f32_fp8((int)u.x, true);
    const f32x2 v45 = __builtin_amdgcn_cvt_pk_f32_fp8((int)u.y, false);
    const f32x2 v67 = __builtin_amdgcn_cvt_pk_f32_fp8((int)u.y, true);
    float dot = v01.x * s0;
    dot = fmaf(v01.y, s1, dot); dot = fmaf(v23.x, s2, dot);
    dot = fmaf(v23.y, s3, dot); dot = fmaf(v45.x, s4, dot);
    dot = fmaf(v45.y, s5, dot); dot = fmaf(v67.x, s6, dot);
    dot = fmaf(v67.y, s7, dot);
    const float p = __expf(lrelu(dot + adT));
    a0 = fmaf(p, v01.x, a0); a1 = fmaf(p, v01.y, a1);
    a2 = fmaf(p, v23.x, a2); a3 = fmaf(p, v23.y, a3);
    a4 = fmaf(p, v45.x, a4); a5 = fmaf(p, v45.y, a5);
    a6 = fmaf(p, v67.x, a6); a7 = fmaf(p, v67.y, a7);
    den += p;
  }
#pragma unroll
  for (int off = 8; off < 64; off <<= 1) {
    a0 += __shfl_xor(a0, off); a1 += __shfl_xor(a1, off);
    a2 += __shfl_xor(a2, off); a3 += __shfl_xor(a3, off);
    a4 += __shfl_xor(a4, off); a5 += __shfl_xor(a5, off);
    a6 += __shfl_xor(a6, off); a7 += __shfl_xor(a7, off);
    den += __shfl_xor(den, off);
  }
  if (eslot == 0) {
    const float inv16 = 1.f / den * 0.0625f;
    uint4 w;
    w.x = f2bf(a0 * inv16) | (f2bf(a1 * inv16) << 16);
    w.y = f2bf(a2 * inv16) | (f2bf(a3 * inv16) << 16);
    w.z = f2bf(a4 * inv16) | (f2bf(a5 * inv16) << 16);
    w.w = f2bf(a6 * inv16) | (f2bf(a7 * inv16) << 16);
    *(uint4*)(xp1h + (size_t)d * 128 + (h << 4)) = w;
  }
}

// ---- P2: dense h=elu(hpre+b1); xp2=h@W2; write segmented 64B xp2 row ------
__global__ __launch_bounds__(256) void k_proj2(
    const unsigned char* __restrict__ xp1h, const float* __restrict__ b1,
    const float* __restrict__ W2, const float* __restrict__ a_src2,
    const float* __restrict__ a_dst2,
    unsigned int* __restrict__ xp2b, float* __restrict__ adst2, int n)
{
  __shared__ float sW[64 * 20];
  for (int i = threadIdx.x; i < 64 * 20; i += 256) sW[i] = W2[i];
  __syncthreads();
  const int node = blockIdx.x * 64 + (threadIdx.x >> 2);
  const int part = threadIdx.x & 3;
  if (node >= n) return;
  const int k0 = part * 16;
  const uint4 u0 = *(const uint4*)(xp1h + (size_t)node * 128 + k0 * 2);
  const uint4 u1 = *(const uint4*)(xp1h + (size_t)node * 128 + k0 * 2 + 16);
  float hv[16];
  {
    const unsigned uu[8] = {u0.x,u0.y,u0.z,u0.w,u1.x,u1.y,u1.z,u1.w};
#pragma unroll
    for (int j = 0; j < 8; ++j) {
      float t0 = __uint_as_float(uu[j] << 16)        + b1[k0 + 2*j];
      float t1 = __uint_as_float(uu[j] & 0xFFFF0000u) + b1[k0 + 2*j + 1];
      hv[2*j]   = t0 > 0.f ? t0 : expm1f(t0);
      hv[2*j+1] = t1 > 0.f ? t1 : expm1f(t1);
    }
  }
  float acc[20];
#pragma unroll
  for (int c = 0; c < 20; ++c) acc[c] = 0.f;
#pragma unroll
  for (int j = 0; j < 16; ++j) {
    const float hj = hv[j];
    const float* wr = sW + (k0 + j) * 20;
#pragma unroll
    for (int c = 0; c < 20; ++c) acc[c] = fmaf(hj, wr[c], acc[c]);
  }
#pragma unroll
  for (int c = 0; c < 20; ++c) {
    acc[c] += __shfl_xor(acc[c], 1);
    acc[c] += __shfl_xor(acc[c], 2);
  }
  float vs = 0.f, vd = 0.f;
#pragma unroll
  for (int c = 0; c < 20; ++c) {
    vs = fmaf(acc[c], a_src2[c], vs);
    vd = fmaf(acc[c], a_dst2[c], vd);
  }
  const int p5 = part * 5;
  uint4 w;
  w.x = f2bf(acc[p5 + 0]) | (f2bf(acc[p5 + 1]) << 16);
  w.y = f2bf(acc[p5 + 2]) | (f2bf(acc[p5 + 3]) << 16);
  w.z = f2bf(acc[p5 + 4]);
  w.w = __float_as_uint(vs);
  *(uint4*)(xp2b + (size_t)node * 16 + part * 4) = w;
  if (part == 0) adst2[node] = vd;
}

// ---- G2: layer-2 gather (16 edges/wave, segment rows) + log_softmax -------
__global__ __launch_bounds__(256) void k_gather2(
    const int* __restrict__ offs, const int* __restrict__ csr,
    const float* __restrict__ adst2,
    const unsigned char* __restrict__ xp2c, const float* __restrict__ b2,
    float* __restrict__ out, int n)
{
  const int wid = threadIdx.x >> 6, ln = threadIdx.x & 63;
  const int eslot = ln >> 2, q = ln & 3;
  const int d = blockIdx.x * 4 + wid;
  if (d >= n) return;
  const int beg = offs[d], end = offs[d + 1];
  const float adT = adst2[d];
  const int qoff = q << 4;
  float a0=0.f,a1=0.f,a2=0.f,a3=0.f,a4=0.f,den=0.f;
#pragma unroll 2
  for (int jb = beg + eslot; jb < end; jb += 16) {
    const int sv = __builtin_nontemporal_load(&csr[jb]);   // src<<6
    const uint4 u = *(const uint4*)(xp2c + (unsigned)sv + qoff);
    const float p = __expf(lrelu(__uint_as_float(u.w) + adT));
    a0 = fmaf(p, __uint_as_float(u.x << 16), a0);
    a1 = fmaf(p, __uint_as_float(u.x & 0xFFFF0000u), a1);
    a2 = fmaf(p, __uint_as_float(u.y << 16), a2);
    a3 = fmaf(p, __uint_as_float(u.y & 0xFFFF0000u), a3);
    a4 = fmaf(p, __uint_as_float(u.z << 16), a4);
    den += p;
  }
#pragma unroll
  for (int off = 4; off < 64; off <<= 1) {
    a0 += __shfl_xor(a0, off); a1 += __shfl_xor(a1, off);
    a2 += __shfl_xor(a2, off); a3 += __shfl_xor(a3, off);
    a4 += __shfl_xor(a4, off);
    den += __shfl_xor(den, off);
  }
  const float inv = 1.f / den;
  const int c5 = q * 5;
  float o[5];
  float mx;
  {
    o[0] = a0 * inv + b2[c5 + 0];
    o[1] = a1 * inv + b2[c5 + 1];
    o[2] = a2 * inv + b2[c5 + 2];
    o[3] = a3 * inv + b2[c5 + 3];
    o[4] = a4 * inv + b2[c5 + 4];
    mx = fmaxf(fmaxf(fmaxf(o[0], o[1]), fmaxf(o[2], o[3])), o[4]);
  }
  mx = fmaxf(mx, __shfl_xor(mx, 1));
  mx = fmaxf(mx, __shfl_xor(mx, 2));
  float ss = __expf(o[0] - mx) + __expf(o[1] - mx) + __expf(o[2] - mx)
           + __expf(o[3] - mx) + __expf(o[4] - mx);
  ss += __shfl_xor(ss, 1);
  ss += __shfl_xor(ss, 2);
  const float lse = mx + __logf(ss);
  if (eslot == 0) {
#pragma unroll
    for (int j = 0; j < 5; ++j)
      out[(size_t)d * 20 + c5 + j] = o[j] - lse;
  }
}

// ---------------------------------------------------------------------------

extern "C" void kernel_launch(void* const* d_in, const int* in_sizes, int n_in,
                              void* d_out, int out_size, void* d_ws, size_t ws_size,
                              hipStream_t stream)
{
  const int*   x_ids  = (const int*)d_in[0];
  const int*   ei     = (const int*)d_in[1];   // [2,E]: [0..E)=src, [E..2E)=dst
  const float* emb    = (const float*)d_in[2];
  const float* W1     = (const float*)d_in[3];
  const float* a_src1 = (const float*)d_in[4];
  const float* a_dst1 = (const float*)d_in[5];
  const float* b1     = (const float*)d_in[6];
  const float* W2     = (const float*)d_in[7];
  const float* a_src2 = (const float*)d_in[8];
  const float* a_dst2 = (const float*)d_in[9];
  const float* b2     = (const float*)d_in[10];
  float* out = (float*)d_out;

  const int n = in_sizes[0];
  const int E = in_sizes[1] / 2;
  const int nb = (n + 255) >> 8;               // buckets of 256 dst ids

  // workspace layout (bytes). xp1f8 aliases buf (build-phase only).
  char* base = (char*)d_ws;
  size_t r0 = (size_t)n * 64;                  // xp1f8: n*64*1 B
  if ((size_t)E * 4 > r0) r0 = (size_t)E * 4;  // buf:  E*4 B
  r0 = (r0 + 255) & ~(size_t)255;
  unsigned char* xp1f8 = (unsigned char*)base;
  int*   buf   = (int*)base;
  float* adst1 = (float*)(base + r0);                    // n*8 f32
  unsigned char* xp1h = (unsigned char*)(adst1 + (size_t)n * 8); // n*128 B
  unsigned int* xp2b = (unsigned int*)(xp1h + (size_t)n * 128);  // n*16 uint
  float* adst2 = (float*)(xp2b + (size_t)n * 16);        // n
  int*   offs   = (int*)(adst2 + (size_t)n);   // n+1
  int*   bhistP = offs + n + 1;                // NHB*256 (all slots written)
  int*   bufOffs= bhistP + NHB * 256;          // nb+1
  int*   tail   = bufOffs + 257;               // 256
  int*   csr    = tail + 256;                  // E+n

  k_bhist<<<NHB, 256, 0, stream>>>(ei, bhistP, E);
  k_bscan<<<1, 256, 0, stream>>>(bhistP, bufOffs, tail, nb);
  k_part<<<(E + EPB - 1) / EPB, 256, 0, stream>>>(ei, tail, buf, E);
  k_coffs_scat<<<nb, 256, 0, stream>>>(buf, bufOffs, offs, csr, n);

  k_embed_proj1<<<(n + 31) / 32, 256, 0, stream>>>(
      x_ids, emb, W1, a_dst1, xp1f8, adst1, n);

  k_gather1<<<(n + 3) / 4, 256, 0, stream>>>(
      offs, csr, a_src1, adst1, xp1f8, xp1h, n);

  k_proj2<<<(n + 63) / 64, 256, 0, stream>>>(
      xp1h, b1, W2, a_src2, a_dst2, xp2b, adst2, n);

  k_gather2<<<(n + 3) / 4, 256, 0, stream>>>(
      offs, csr, adst2, (const unsigned char*)xp2b, b2, out, n);
}

// Round 17
// 187.617 us; speedup vs baseline: 1.1653x; 1.1653x over previous
//
#include <hip/hip_runtime.h>
#include <cstddef>

// ---------------------------------------------------------------------------
// 2-layer GAT forward, CSR-gather formulation.
// R17: k_bhist back to 256 blocks (R16's NHB=64 was 2.3%-occupancy
// latency-bound, 43us), 4-way unrolled loads; still partial-histogram
// (no memset, no global atomics). k_bscan sums 256 partials. Rest = R16.
// Requires n < 65536.
// ---------------------------------------------------------------------------

#define EPB 2048   // edges per k_part block
#define NHB 256    // histogram partial blocks

typedef float f32x2 __attribute__((ext_vector_type(2)));

__device__ __forceinline__ float lrelu(float x) { return x > 0.f ? x : 0.2f * x; }
__device__ __forceinline__ int iadd(int* p, int v) {
  return __hip_atomic_fetch_add(p, v, __ATOMIC_RELAXED, __HIP_MEMORY_SCOPE_AGENT);
}
__device__ __forceinline__ unsigned f2bf(float f) {         // RNE float->bf16
  unsigned int u = __float_as_uint(f);
  u += 0x7FFFu + ((u >> 16) & 1u);
  return u >> 16;
}

// ---- CSR build ------------------------------------------------------------

// per-block partial histograms; every slot written -> no pre-zeroing needed
__global__ __launch_bounds__(256) void k_bhist(
    const int* __restrict__ ei, int* __restrict__ bhistP, int E)
{
  __shared__ int h[256];
  h[threadIdx.x] = 0; __syncthreads();
  const int stride = NHB * 256;
  int e = blockIdx.x * 256 + threadIdx.x;
  // 4-way unrolled: 4 independent loads in flight before LDS atomics
  for (; e + 3 * stride < E; e += 4 * stride) {
    int d0 = ei[E + e];
    int d1 = ei[E + e + stride];
    int d2 = ei[E + e + 2 * stride];
    int d3 = ei[E + e + 3 * stride];
    atomicAdd(&h[d0 >> 8], 1);
    atomicAdd(&h[d1 >> 8], 1);
    atomicAdd(&h[d2 >> 8], 1);
    atomicAdd(&h[d3 >> 8], 1);
  }
  for (; e < E; e += stride)
    atomicAdd(&h[ei[E + e] >> 8], 1);
  __syncthreads();
  bhistP[(blockIdx.x << 8) + threadIdx.x] = h[threadIdx.x];
}

// reduce partials + scan bucket sizes -> bufOffs[0..nb], tails
__global__ __launch_bounds__(256) void k_bscan(
    const int* __restrict__ bhistP, int* __restrict__ bufOffs,
    int* __restrict__ tail, int nb)
{
  __shared__ int sp[256];
  const int tid = threadIdx.x;
  int v = 0;
#pragma unroll 8
  for (int b = 0; b < NHB; ++b) v += bhistP[(b << 8) + tid];
  sp[tid] = v; __syncthreads();
  for (int off = 1; off < 256; off <<= 1) {
    int t = (tid >= off) ? sp[tid - off] : 0;
    __syncthreads();
    sp[tid] += t;
    __syncthreads();
  }
  int excl = sp[tid] - v;
  if (tid < nb) { bufOffs[tid] = excl; tail[tid] = excl; }
  if (tid == 255) bufOffs[nb] = sp[255];
}

__global__ __launch_bounds__(256) void k_part(
    const int* __restrict__ ei, int* __restrict__ tail,
    int* __restrict__ buf, int E)
{
  __shared__ int sPair[EPB];
  __shared__ unsigned char sKey[EPB];
  __shared__ int sHist[256];
  __shared__ int sBase[256];
  const int tid = threadIdx.x;
  sHist[tid] = 0; __syncthreads();
  const int e0 = blockIdx.x * EPB;
  int m = E - e0; if (m > EPB) m = EPB;
  for (int i = tid; i < m; i += 256) {
    int d = __builtin_nontemporal_load(&ei[E + e0 + i]);
    int s = __builtin_nontemporal_load(&ei[e0 + i]);
    sPair[i] = ((d & 255) << 16) | s;
    int b = d >> 8;
    sKey[i] = (unsigned char)b;
    atomicAdd(&sHist[b], 1);
  }
  __syncthreads();
  int c = sHist[tid];
  sBase[tid] = c ? iadd(&tail[tid], c) : 0;
  sHist[tid] = 0;
  __syncthreads();
  for (int i = tid; i < m; i += 256) {
    int b = sKey[i];
    int off = atomicAdd(&sHist[b], 1);
    buf[sBase[b] + off] = sPair[i];
  }
}

// per-bucket: LDS hist (incl. self-loop) + scan -> offs, then LDS-cursor
// scatter into csr. csr holds src<<6 (pre-scaled byte offset for 64B rows).
__global__ __launch_bounds__(256) void k_coffs_scat(
    const int* __restrict__ buf, const int* __restrict__ bufOffs,
    int* __restrict__ offs, int* __restrict__ csr, int n)
{
  __shared__ int h[256];
  __shared__ int cur[256];
  const int b = blockIdx.x, tid = threadIdx.x;
  const int d = (b << 8) + tid;
  h[tid] = (d < n) ? 1 : 0;
  __syncthreads();
  const int lo = bufOffs[b], hi = bufOffs[b + 1];
  for (int i = lo + tid; i < hi; i += 256)
    atomicAdd(&h[(buf[i] >> 16) & 255], 1);
  __syncthreads();
  const int cnt = h[tid];
  for (int off = 1; off < 256; off <<= 1) {
    int t = (tid >= off) ? h[tid - off] : 0;
    __syncthreads();
    h[tid] += t;
    __syncthreads();
  }
  const int excl = h[tid] - cnt;
  const int base = lo + (b << 8);
  if (d < n) {
    const int o = base + excl;
    offs[d] = o;
    csr[o] = d << 6;                    // self-loop first
    cur[tid] = o + 1;
    if (d == n - 1) offs[n] = o + cnt;
  }
  __syncthreads();
  for (int i = lo + tid; i < hi; i += 256) {
    int p = buf[i];
    int pos = atomicAdd(&cur[(p >> 16) & 255], 1);
    csr[pos] = (p & 0xFFFF) << 6;
  }
}

// ---- K1: embedding gather + x@W1 (128->64). Barrier-free, prefetched. -----
__global__ __launch_bounds__(256) void k_embed_proj1(
    const int* __restrict__ x_ids, const float* __restrict__ emb,
    const float* __restrict__ W1, const float* __restrict__ a_dst1,
    unsigned char* __restrict__ xp1f8, float* __restrict__ adst1, int n)
{
  __shared__ float sWT[64 * 132];          // transposed W1, pad 132 (16B align)
  __shared__ float sx[4][2][128];          // per-wave slot [wid][node][k]
  for (int i = threadIdx.x; i < 128 * 64; i += 256) {
    int k = i >> 6, c = i & 63;
    sWT[c * 132 + k] = W1[i];
  }
  __syncthreads();                         // the ONLY block barrier
  const int wid = threadIdx.x >> 6;
  const int ln  = threadIdx.x & 63;
  const int ch  = ln;
  const int hh = ch >> 3, cc = ch & 7;
  const float ad = a_dst1[ch];
  const float* wrow = sWT + ch * 132;
  const int half = ln >> 5;
  const int qk   = ln & 31;
  float* myx = &sx[wid][0][0];
  // prefetch g=0 row
  float4 xv = make_float4(0.f, 0.f, 0.f, 0.f);
  {
    const int node_s = blockIdx.x * 32 + wid * 2 + half;
    if (node_s < n)
      xv = *(const float4*)(emb + (size_t)x_ids[node_s] * 128 + qk * 4);
  }
  for (int g = 0; g < 4; ++g) {
    *(float4*)(myx + half * 128 + qk * 4) = xv;   // vmcnt wait hidden
    float4 xnext = make_float4(0.f, 0.f, 0.f, 0.f);
    if (g < 3) {
      const int node_s = blockIdx.x * 32 + (g + 1) * 8 + wid * 2 + half;
      if (node_s < n)
        xnext = *(const float4*)(emb + (size_t)x_ids[node_s] * 128 + qk * 4);
    }
    asm volatile("s_waitcnt lgkmcnt(0)" ::: "memory");
    const int node0 = blockIdx.x * 32 + g * 8 + wid * 2;
    float acc0 = 0.f, acc1 = 0.f;
#pragma unroll 8
    for (int k = 0; k < 128; k += 4) {
      const float4 wv = *(const float4*)(wrow + k);
      const float4 x0 = *(const float4*)(myx + k);
      const float4 x1 = *(const float4*)(myx + 128 + k);
      acc0 = fmaf(x0.x, wv.x, acc0); acc1 = fmaf(x1.x, wv.x, acc1);
      acc0 = fmaf(x0.y, wv.y, acc0); acc1 = fmaf(x1.y, wv.y, acc1);
      acc0 = fmaf(x0.z, wv.z, acc0); acc1 = fmaf(x1.z, wv.z, acc1);
      acc0 = fmaf(x0.w, wv.w, acc0); acc1 = fmaf(x1.w, wv.w, acc1);
    }
    float vd0 = acc0 * ad, vd1 = acc1 * ad;
    vd0 += __shfl_xor(vd0, 1); vd0 += __shfl_xor(vd0, 2); vd0 += __shfl_xor(vd0, 4);
    vd1 += __shfl_xor(vd1, 1); vd1 += __shfl_xor(vd1, 2); vd1 += __shfl_xor(vd1, 4);
    const int node1 = node0 + 1;
    if (node0 < n) {
      unsigned int pk = (unsigned int)__builtin_amdgcn_cvt_pk_fp8_f32(
          acc0 * 16.f, acc0 * 16.f, 0, false);
      xp1f8[(size_t)node0 * 64 + ch] = (unsigned char)pk;
      if (cc == 0) adst1[node0 * 8 + hh] = vd0;
    }
    if (node1 < n) {
      unsigned int pk = (unsigned int)__builtin_amdgcn_cvt_pk_fp8_f32(
          acc1 * 16.f, acc1 * 16.f, 0, false);
      xp1f8[(size_t)node1 * 64 + ch] = (unsigned char)pk;
      if (cc == 0) adst1[node1 * 8 + hh] = vd1;
    }
    asm volatile("s_waitcnt lgkmcnt(0)" ::: "memory");
    xv = xnext;
  }
}

// ---- G1: pure layer-1 gather. No LDS, no barrier, 4 independent waves. ----
__global__ __launch_bounds__(256) void k_gather1(
    const int* __restrict__ offs, const int* __restrict__ csr,
    const float* __restrict__ a_src1, const float* __restrict__ adst1,
    const unsigned char* __restrict__ xp1f8,
    unsigned char* __restrict__ xp1h, int n)
{
  const int wid = threadIdx.x >> 6;
  const int ln  = threadIdx.x & 63;
  const int eslot = ln >> 3;
  const int h     = ln & 7;
  const int c0    = h << 3;
  const int d = blockIdx.x * 4 + wid;
  if (d >= n) return;
  const float4 a1lo0 = *(const float4*)(a_src1 + c0);
  const float4 a1hi0 = *(const float4*)(a_src1 + c0 + 4);
  const float s0 = a1lo0.x * 0.0625f, s1 = a1lo0.y * 0.0625f;
  const float s2 = a1lo0.z * 0.0625f, s3 = a1lo0.w * 0.0625f;
  const float s4 = a1hi0.x * 0.0625f, s5 = a1hi0.y * 0.0625f;
  const float s6 = a1hi0.z * 0.0625f, s7 = a1hi0.w * 0.0625f;
  const int beg = offs[d], end = offs[d + 1];
  const float adT = adst1[(size_t)d * 8 + h];
  const int hoff = h << 3;
  float a0=0.f,a1=0.f,a2=0.f,a3=0.f,a4=0.f,a5=0.f,a6=0.f,a7=0.f,den=0.f;
#pragma unroll 4
  for (int jb = beg + eslot; jb < end; jb += 8) {
    const int sv = __builtin_nontemporal_load(&csr[jb]);   // src<<6
    const uint2 u = *(const uint2*)(xp1f8 + (unsigned)sv + hoff);
    const f32x2 v01 = __builtin_amdgcn_cvt_pk_f32_fp8((int)u.x, false);
    const f32x2 v23 = __builtin_amdgcn_cvt_pk_f32_fp8((int)u.x, true);
    const f32x2 v45 = __builtin_amdgcn_cvt_pk_f32_fp8((int)u.y, false);
    const f32x2 v67 = __builtin_amdgcn_cvt_pk_f32_fp8((int)u.y, true);
    float dot = v01.x * s0;
    dot = fmaf(v01.y, s1, dot); dot = fmaf(v23.x, s2, dot);
    dot = fmaf(v23.y, s3, dot); dot = fmaf(v45.x, s4, dot);
    dot = fmaf(v45.y, s5, dot); dot = fmaf(v67.x, s6, dot);
    dot = fmaf(v67.y, s7, dot);
    const float p = __expf(lrelu(dot + adT));
    a0 = fmaf(p, v01.x, a0); a1 = fmaf(p, v01.y, a1);
    a2 = fmaf(p, v23.x, a2); a3 = fmaf(p, v23.y, a3);
    a4 = fmaf(p, v45.x, a4); a5 = fmaf(p, v45.y, a5);
    a6 = fmaf(p, v67.x, a6); a7 = fmaf(p, v67.y, a7);
    den += p;
  }
#pragma unroll
  for (int off = 8; off < 64; off <<= 1) {
    a0 += __shfl_xor(a0, off); a1 += __shfl_xor(a1, off);
    a2 += __shfl_xor(a2, off); a3 += __shfl_xor(a3, off);
    a4 += __shfl_xor(a4, off); a5 += __shfl_xor(a5, off);
    a6 += __shfl_xor(a6, off); a7 += __shfl_xor(a7, off);
    den += __shfl_xor(den, off);
  }
  if (eslot == 0) {
    const float inv16 = 1.f / den * 0.0625f;
    uint4 w;
    w.x = f2bf(a0 * inv16) | (f2bf(a1 * inv16) << 16);
    w.y = f2bf(a2 * inv16) | (f2bf(a3 * inv16) << 16);
    w.z = f2bf(a4 * inv16) | (f2bf(a5 * inv16) << 16);
    w.w = f2bf(a6 * inv16) | (f2bf(a7 * inv16) << 16);
    *(uint4*)(xp1h + (size_t)d * 128 + (h << 4)) = w;
  }
}

// ---- P2: dense h=elu(hpre+b1); xp2=h@W2; write segmented 64B xp2 row ------
__global__ __launch_bounds__(256) void k_proj2(
    const unsigned char* __restrict__ xp1h, const float* __restrict__ b1,
    const float* __restrict__ W2, const float* __restrict__ a_src2,
    const float* __restrict__ a_dst2,
    unsigned int* __restrict__ xp2b, float* __restrict__ adst2, int n)
{
  __shared__ float sW[64 * 20];
  for (int i = threadIdx.x; i < 64 * 20; i += 256) sW[i] = W2[i];
  __syncthreads();
  const int node = blockIdx.x * 64 + (threadIdx.x >> 2);
  const int part = threadIdx.x & 3;
  if (node >= n) return;
  const int k0 = part * 16;
  const uint4 u0 = *(const uint4*)(xp1h + (size_t)node * 128 + k0 * 2);
  const uint4 u1 = *(const uint4*)(xp1h + (size_t)node * 128 + k0 * 2 + 16);
  float hv[16];
  {
    const unsigned uu[8] = {u0.x,u0.y,u0.z,u0.w,u1.x,u1.y,u1.z,u1.w};
#pragma unroll
    for (int j = 0; j < 8; ++j) {
      float t0 = __uint_as_float(uu[j] << 16)        + b1[k0 + 2*j];
      float t1 = __uint_as_float(uu[j] & 0xFFFF0000u) + b1[k0 + 2*j + 1];
      hv[2*j]   = t0 > 0.f ? t0 : expm1f(t0);
      hv[2*j+1] = t1 > 0.f ? t1 : expm1f(t1);
    }
  }
  float acc[20];
#pragma unroll
  for (int c = 0; c < 20; ++c) acc[c] = 0.f;
#pragma unroll
  for (int j = 0; j < 16; ++j) {
    const float hj = hv[j];
    const float* wr = sW + (k0 + j) * 20;
#pragma unroll
    for (int c = 0; c < 20; ++c) acc[c] = fmaf(hj, wr[c], acc[c]);
  }
#pragma unroll
  for (int c = 0; c < 20; ++c) {
    acc[c] += __shfl_xor(acc[c], 1);
    acc[c] += __shfl_xor(acc[c], 2);
  }
  float vs = 0.f, vd = 0.f;
#pragma unroll
  for (int c = 0; c < 20; ++c) {
    vs = fmaf(acc[c], a_src2[c], vs);
    vd = fmaf(acc[c], a_dst2[c], vd);
  }
  const int p5 = part * 5;
  uint4 w;
  w.x = f2bf(acc[p5 + 0]) | (f2bf(acc[p5 + 1]) << 16);
  w.y = f2bf(acc[p5 + 2]) | (f2bf(acc[p5 + 3]) << 16);
  w.z = f2bf(acc[p5 + 4]);
  w.w = __float_as_uint(vs);
  *(uint4*)(xp2b + (size_t)node * 16 + part * 4) = w;
  if (part == 0) adst2[node] = vd;
}

// ---- G2: layer-2 gather (16 edges/wave, segment rows) + log_softmax -------
__global__ __launch_bounds__(256) void k_gather2(
    const int* __restrict__ offs, const int* __restrict__ csr,
    const float* __restrict__ adst2,
    const unsigned char* __restrict__ xp2c, const float* __restrict__ b2,
    float* __restrict__ out, int n)
{
  const int wid = threadIdx.x >> 6, ln = threadIdx.x & 63;
  const int eslot = ln >> 2, q = ln & 3;
  const int d = blockIdx.x * 4 + wid;
  if (d >= n) return;
  const int beg = offs[d], end = offs[d + 1];
  const float adT = adst2[d];
  const int qoff = q << 4;
  float a0=0.f,a1=0.f,a2=0.f,a3=0.f,a4=0.f,den=0.f;
#pragma unroll 2
  for (int jb = beg + eslot; jb < end; jb += 16) {
    const int sv = __builtin_nontemporal_load(&csr[jb]);   // src<<6
    const uint4 u = *(const uint4*)(xp2c + (unsigned)sv + qoff);
    const float p = __expf(lrelu(__uint_as_float(u.w) + adT));
    a0 = fmaf(p, __uint_as_float(u.x << 16), a0);
    a1 = fmaf(p, __uint_as_float(u.x & 0xFFFF0000u), a1);
    a2 = fmaf(p, __uint_as_float(u.y << 16), a2);
    a3 = fmaf(p, __uint_as_float(u.y & 0xFFFF0000u), a3);
    a4 = fmaf(p, __uint_as_float(u.z << 16), a4);
    den += p;
  }
#pragma unroll
  for (int off = 4; off < 64; off <<= 1) {
    a0 += __shfl_xor(a0, off); a1 += __shfl_xor(a1, off);
    a2 += __shfl_xor(a2, off); a3 += __shfl_xor(a3, off);
    a4 += __shfl_xor(a4, off);
    den += __shfl_xor(den, off);
  }
  const float inv = 1.f / den;
  const int c5 = q * 5;
  float o[5];
  float mx;
  {
    o[0] = a0 * inv + b2[c5 + 0];
    o[1] = a1 * inv + b2[c5 + 1];
    o[2] = a2 * inv + b2[c5 + 2];
    o[3] = a3 * inv + b2[c5 + 3];
    o[4] = a4 * inv + b2[c5 + 4];
    mx = fmaxf(fmaxf(fmaxf(o[0], o[1]), fmaxf(o[2], o[3])), o[4]);
  }
  mx = fmaxf(mx, __shfl_xor(mx, 1));
  mx = fmaxf(mx, __shfl_xor(mx, 2));
  float ss = __expf(o[0] - mx) + __expf(o[1] - mx) + __expf(o[2] - mx)
           + __expf(o[3] - mx) + __expf(o[4] - mx);
  ss += __shfl_xor(ss, 1);
  ss += __shfl_xor(ss, 2);
  const float lse = mx + __logf(ss);
  if (eslot == 0) {
#pragma unroll
    for (int j = 0; j < 5; ++j)
      out[(size_t)d * 20 + c5 + j] = o[j] - lse;
  }
}

// ---------------------------------------------------------------------------

extern "C" void kernel_launch(void* const* d_in, const int* in_sizes, int n_in,
                              void* d_out, int out_size, void* d_ws, size_t ws_size,
                              hipStream_t stream)
{
  const int*   x_ids  = (const int*)d_in[0];
  const int*   ei     = (const int*)d_in[1];   // [2,E]: [0..E)=src, [E..2E)=dst
  const float* emb    = (const float*)d_in[2];
  const float* W1     = (const float*)d_in[3];
  const float* a_src1 = (const float*)d_in[4];
  const float* a_dst1 = (const float*)d_in[5];
  const float* b1     = (const float*)d_in[6];
  const float* W2     = (const float*)d_in[7];
  const float* a_src2 = (const float*)d_in[8];
  const float* a_dst2 = (const float*)d_in[9];
  const float* b2     = (const float*)d_in[10];
  float* out = (float*)d_out;

  const int n = in_sizes[0];
  const int E = in_sizes[1] / 2;
  const int nb = (n + 255) >> 8;               // buckets of 256 dst ids

  // workspace layout (bytes). xp1f8 aliases buf (build-phase only).
  char* base = (char*)d_ws;
  size_t r0 = (size_t)n * 64;                  // xp1f8: n*64*1 B
  if ((size_t)E * 4 > r0) r0 = (size_t)E * 4;  // buf:  E*4 B
  r0 = (r0 + 255) & ~(size_t)255;
  unsigned char* xp1f8 = (unsigned char*)base;
  int*   buf   = (int*)base;
  float* adst1 = (float*)(base + r0);                    // n*8 f32
  unsigned char* xp1h = (unsigned char*)(adst1 + (size_t)n * 8); // n*128 B
  unsigned int* xp2b = (unsigned int*)(xp1h + (size_t)n * 128);  // n*16 uint
  float* adst2 = (float*)(xp2b + (size_t)n * 16);        // n
  int*   offs   = (int*)(adst2 + (size_t)n);   // n+1
  int*   bhistP = offs + n + 1;                // NHB*256 (all slots written)
  int*   bufOffs= bhistP + NHB * 256;          // nb+1
  int*   tail   = bufOffs + 257;               // 256
  int*   csr    = tail + 256;                  // E+n

  k_bhist<<<NHB, 256, 0, stream>>>(ei, bhistP, E);
  k_bscan<<<1, 256, 0, stream>>>(bhistP, bufOffs, tail, nb);
  k_part<<<(E + EPB - 1) / EPB, 256, 0, stream>>>(ei, tail, buf, E);
  k_coffs_scat<<<nb, 256, 0, stream>>>(buf, bufOffs, offs, csr, n);

  k_embed_proj1<<<(n + 31) / 32, 256, 0, stream>>>(
      x_ids, emb, W1, a_dst1, xp1f8, adst1, n);

  k_gather1<<<(n + 3) / 4, 256, 0, stream>>>(
      offs, csr, a_src1, adst1, xp1f8, xp1h, n);

  k_proj2<<<(n + 63) / 64, 256, 0, stream>>>(
      xp1h, b1, W2, a_src2, a_dst2, xp2b, adst2, n);

  k_gather2<<<(n + 3) / 4, 256, 0, stream>>>(
      offs, csr, adst2, (const unsigned char*)xp2b, b2, out, n);
}

// Round 18
// 166.638 us; speedup vs baseline: 1.3120x; 1.1259x over previous
//
#include <hip/hip_runtime.h>
#include <cstddef>

// ---------------------------------------------------------------------------
// 2-layer GAT forward, CSR-gather formulation.
// R18: k_coffs_scat fused with k_embed_proj1 into one launch (block-uniform
// branch; shared smem buffer reinterpreted per branch). coffs (~12us) hides
// under embed (~40us); one fewer dispatch. Kernel bodies identical to R17.
// Requires n < 65536.
// ---------------------------------------------------------------------------

#define EPB 2048   // edges per k_part block
#define NHB 256    // histogram partial blocks

typedef float f32x2 __attribute__((ext_vector_type(2)));

__device__ __forceinline__ float lrelu(float x) { return x > 0.f ? x : 0.2f * x; }
__device__ __forceinline__ int iadd(int* p, int v) {
  return __hip_atomic_fetch_add(p, v, __ATOMIC_RELAXED, __HIP_MEMORY_SCOPE_AGENT);
}
__device__ __forceinline__ unsigned f2bf(float f) {         // RNE float->bf16
  unsigned int u = __float_as_uint(f);
  u += 0x7FFFu + ((u >> 16) & 1u);
  return u >> 16;
}

// ---- CSR build ------------------------------------------------------------

// per-block partial histograms; every slot written -> no pre-zeroing needed
__global__ __launch_bounds__(256) void k_bhist(
    const int* __restrict__ ei, int* __restrict__ bhistP, int E)
{
  __shared__ int h[256];
  h[threadIdx.x] = 0; __syncthreads();
  const int stride = NHB * 256;
  int e = blockIdx.x * 256 + threadIdx.x;
  for (; e + 3 * stride < E; e += 4 * stride) {
    int d0 = ei[E + e];
    int d1 = ei[E + e + stride];
    int d2 = ei[E + e + 2 * stride];
    int d3 = ei[E + e + 3 * stride];
    atomicAdd(&h[d0 >> 8], 1);
    atomicAdd(&h[d1 >> 8], 1);
    atomicAdd(&h[d2 >> 8], 1);
    atomicAdd(&h[d3 >> 8], 1);
  }
  for (; e < E; e += stride)
    atomicAdd(&h[ei[E + e] >> 8], 1);
  __syncthreads();
  bhistP[(blockIdx.x << 8) + threadIdx.x] = h[threadIdx.x];
}

// reduce partials + scan bucket sizes -> bufOffs[0..nb], tails
__global__ __launch_bounds__(256) void k_bscan(
    const int* __restrict__ bhistP, int* __restrict__ bufOffs,
    int* __restrict__ tail, int nb)
{
  __shared__ int sp[256];
  const int tid = threadIdx.x;
  int v = 0;
#pragma unroll 8
  for (int b = 0; b < NHB; ++b) v += bhistP[(b << 8) + tid];
  sp[tid] = v; __syncthreads();
  for (int off = 1; off < 256; off <<= 1) {
    int t = (tid >= off) ? sp[tid - off] : 0;
    __syncthreads();
    sp[tid] += t;
    __syncthreads();
  }
  int excl = sp[tid] - v;
  if (tid < nb) { bufOffs[tid] = excl; tail[tid] = excl; }
  if (tid == 255) bufOffs[nb] = sp[255];
}

__global__ __launch_bounds__(256) void k_part(
    const int* __restrict__ ei, int* __restrict__ tail,
    int* __restrict__ buf, int E)
{
  __shared__ int sPair[EPB];
  __shared__ unsigned char sKey[EPB];
  __shared__ int sHist[256];
  __shared__ int sBase[256];
  const int tid = threadIdx.x;
  sHist[tid] = 0; __syncthreads();
  const int e0 = blockIdx.x * EPB;
  int m = E - e0; if (m > EPB) m = EPB;
  for (int i = tid; i < m; i += 256) {
    int d = __builtin_nontemporal_load(&ei[E + e0 + i]);
    int s = __builtin_nontemporal_load(&ei[e0 + i]);
    sPair[i] = ((d & 255) << 16) | s;
    int b = d >> 8;
    sKey[i] = (unsigned char)b;
    atomicAdd(&sHist[b], 1);
  }
  __syncthreads();
  int c = sHist[tid];
  sBase[tid] = c ? iadd(&tail[tid], c) : 0;
  sHist[tid] = 0;
  __syncthreads();
  for (int i = tid; i < m; i += 256) {
    int b = sKey[i];
    int off = atomicAdd(&sHist[b], 1);
    buf[sBase[b] + off] = sPair[i];
  }
}

// ---- FUSED: [blocks 0..nb) = coffs_scat  |  blocks nb.. = embed_proj1 -----
// coffs: per-bucket LDS hist + scan -> offs, LDS-cursor scatter into csr
//        (csr holds src<<6). embed: gather emb rows + x@W1 -> fp8 xp1 + adst1.
__global__ __launch_bounds__(256) void k_coffs_embed(
    // coffs args
    const int* __restrict__ buf, const int* __restrict__ bufOffs,
    int* __restrict__ offs, int* __restrict__ csr, int nb,
    // embed args
    const int* __restrict__ x_ids, const float* __restrict__ emb,
    const float* __restrict__ W1, const float* __restrict__ a_dst1,
    unsigned char* __restrict__ xp1f8, float* __restrict__ adst1, int n)
{
  __shared__ __align__(16) char smem[37888];   // union of both branches
  if ((int)blockIdx.x < nb) {
    // ---------------- coffs_scat branch (2KB of smem) ----------------
    int* h   = (int*)smem;          // 256
    int* cur = h + 256;             // 256
    const int b = blockIdx.x, tid = threadIdx.x;
    const int d = (b << 8) + tid;
    h[tid] = (d < n) ? 1 : 0;
    __syncthreads();
    const int lo = bufOffs[b], hi = bufOffs[b + 1];
    for (int i = lo + tid; i < hi; i += 256)
      atomicAdd(&h[(buf[i] >> 16) & 255], 1);
    __syncthreads();
    const int cnt = h[tid];
    for (int off = 1; off < 256; off <<= 1) {
      int t = (tid >= off) ? h[tid - off] : 0;
      __syncthreads();
      h[tid] += t;
      __syncthreads();
    }
    const int excl = h[tid] - cnt;
    const int base = lo + (b << 8);
    if (d < n) {
      const int o = base + excl;
      offs[d] = o;
      csr[o] = d << 6;                  // self-loop first
      cur[tid] = o + 1;
      if (d == n - 1) offs[n] = o + cnt;
    }
    __syncthreads();
    for (int i = lo + tid; i < hi; i += 256) {
      int p = buf[i];
      int pos = atomicAdd(&cur[(p >> 16) & 255], 1);
      csr[pos] = (p & 0xFFFF) << 6;
    }
    return;
  }
  // ---------------- embed branch (37.9KB of smem) ----------------
  float* sWT = (float*)smem;                    // 64*132 floats
  float* sxb = sWT + 64 * 132;                  // 4*2*128 floats
  const int eb = blockIdx.x - nb;               // embed block index
  for (int i = threadIdx.x; i < 128 * 64; i += 256) {
    int k = i >> 6, c = i & 63;
    sWT[c * 132 + k] = W1[i];
  }
  __syncthreads();                              // the ONLY block barrier
  const int wid = threadIdx.x >> 6;
  const int ln  = threadIdx.x & 63;
  const int ch  = ln;
  const int hh = ch >> 3, cc = ch & 7;
  const float ad = a_dst1[ch];
  const float* wrow = sWT + ch * 132;
  const int half = ln >> 5;
  const int qk   = ln & 31;
  float* myx = sxb + wid * 256;
  float4 xv = make_float4(0.f, 0.f, 0.f, 0.f);
  {
    const int node_s = eb * 32 + wid * 2 + half;
    if (node_s < n)
      xv = *(const float4*)(emb + (size_t)x_ids[node_s] * 128 + qk * 4);
  }
  for (int g = 0; g < 4; ++g) {
    *(float4*)(myx + half * 128 + qk * 4) = xv;
    float4 xnext = make_float4(0.f, 0.f, 0.f, 0.f);
    if (g < 3) {
      const int node_s = eb * 32 + (g + 1) * 8 + wid * 2 + half;
      if (node_s < n)
        xnext = *(const float4*)(emb + (size_t)x_ids[node_s] * 128 + qk * 4);
    }
    asm volatile("s_waitcnt lgkmcnt(0)" ::: "memory");
    const int node0 = eb * 32 + g * 8 + wid * 2;
    float acc0 = 0.f, acc1 = 0.f;
#pragma unroll 8
    for (int k = 0; k < 128; k += 4) {
      const float4 wv = *(const float4*)(wrow + k);
      const float4 x0 = *(const float4*)(myx + k);
      const float4 x1 = *(const float4*)(myx + 128 + k);
      acc0 = fmaf(x0.x, wv.x, acc0); acc1 = fmaf(x1.x, wv.x, acc1);
      acc0 = fmaf(x0.y, wv.y, acc0); acc1 = fmaf(x1.y, wv.y, acc1);
      acc0 = fmaf(x0.z, wv.z, acc0); acc1 = fmaf(x1.z, wv.z, acc1);
      acc0 = fmaf(x0.w, wv.w, acc0); acc1 = fmaf(x1.w, wv.w, acc1);
    }
    float vd0 = acc0 * ad, vd1 = acc1 * ad;
    vd0 += __shfl_xor(vd0, 1); vd0 += __shfl_xor(vd0, 2); vd0 += __shfl_xor(vd0, 4);
    vd1 += __shfl_xor(vd1, 1); vd1 += __shfl_xor(vd1, 2); vd1 += __shfl_xor(vd1, 4);
    const int node1 = node0 + 1;
    if (node0 < n) {
      unsigned int pk = (unsigned int)__builtin_amdgcn_cvt_pk_fp8_f32(
          acc0 * 16.f, acc0 * 16.f, 0, false);
      xp1f8[(size_t)node0 * 64 + ch] = (unsigned char)pk;
      if (cc == 0) adst1[node0 * 8 + hh] = vd0;
    }
    if (node1 < n) {
      unsigned int pk = (unsigned int)__builtin_amdgcn_cvt_pk_fp8_f32(
          acc1 * 16.f, acc1 * 16.f, 0, false);
      xp1f8[(size_t)node1 * 64 + ch] = (unsigned char)pk;
      if (cc == 0) adst1[node1 * 8 + hh] = vd1;
    }
    asm volatile("s_waitcnt lgkmcnt(0)" ::: "memory");
    xv = xnext;
  }
}

// ---- G1: pure layer-1 gather. No LDS, no barrier, 4 independent waves. ----
__global__ __launch_bounds__(256) void k_gather1(
    const int* __restrict__ offs, const int* __restrict__ csr,
    const float* __restrict__ a_src1, const float* __restrict__ adst1,
    const unsigned char* __restrict__ xp1f8,
    unsigned char* __restrict__ xp1h, int n)
{
  const int wid = threadIdx.x >> 6;
  const int ln  = threadIdx.x & 63;
  const int eslot = ln >> 3;
  const int h     = ln & 7;
  const int c0    = h << 3;
  const int d = blockIdx.x * 4 + wid;
  if (d >= n) return;
  const float4 a1lo0 = *(const float4*)(a_src1 + c0);
  const float4 a1hi0 = *(const float4*)(a_src1 + c0 + 4);
  const float s0 = a1lo0.x * 0.0625f, s1 = a1lo0.y * 0.0625f;
  const float s2 = a1lo0.z * 0.0625f, s3 = a1lo0.w * 0.0625f;
  const float s4 = a1hi0.x * 0.0625f, s5 = a1hi0.y * 0.0625f;
  const float s6 = a1hi0.z * 0.0625f, s7 = a1hi0.w * 0.0625f;
  const int beg = offs[d], end = offs[d + 1];
  const float adT = adst1[(size_t)d * 8 + h];
  const int hoff = h << 3;
  float a0=0.f,a1=0.f,a2=0.f,a3=0.f,a4=0.f,a5=0.f,a6=0.f,a7=0.f,den=0.f;
#pragma unroll 4
  for (int jb = beg + eslot; jb < end; jb += 8) {
    const int sv = __builtin_nontemporal_load(&csr[jb]);   // src<<6
    const uint2 u = *(const uint2*)(xp1f8 + (unsigned)sv + hoff);
    const f32x2 v01 = __builtin_amdgcn_cvt_pk_f32_fp8((int)u.x, false);
    const f32x2 v23 = __builtin_amdgcn_cvt_pk_f32_fp8((int)u.x, true);
    const f32x2 v45 = __builtin_amdgcn_cvt_pk_f32_fp8((int)u.y, false);
    const f32x2 v67 = __builtin_amdgcn_cvt_pk_f32_fp8((int)u.y, true);
    float dot = v01.x * s0;
    dot = fmaf(v01.y, s1, dot); dot = fmaf(v23.x, s2, dot);
    dot = fmaf(v23.y, s3, dot); dot = fmaf(v45.x, s4, dot);
    dot = fmaf(v45.y, s5, dot); dot = fmaf(v67.x, s6, dot);
    dot = fmaf(v67.y, s7, dot);
    const float p = __expf(lrelu(dot + adT));
    a0 = fmaf(p, v01.x, a0); a1 = fmaf(p, v01.y, a1);
    a2 = fmaf(p, v23.x, a2); a3 = fmaf(p, v23.y, a3);
    a4 = fmaf(p, v45.x, a4); a5 = fmaf(p, v45.y, a5);
    a6 = fmaf(p, v67.x, a6); a7 = fmaf(p, v67.y, a7);
    den += p;
  }
#pragma unroll
  for (int off = 8; off < 64; off <<= 1) {
    a0 += __shfl_xor(a0, off); a1 += __shfl_xor(a1, off);
    a2 += __shfl_xor(a2, off); a3 += __shfl_xor(a3, off);
    a4 += __shfl_xor(a4, off); a5 += __shfl_xor(a5, off);
    a6 += __shfl_xor(a6, off); a7 += __shfl_xor(a7, off);
    den += __shfl_xor(den, off);
  }
  if (eslot == 0) {
    const float inv16 = 1.f / den * 0.0625f;
    uint4 w;
    w.x = f2bf(a0 * inv16) | (f2bf(a1 * inv16) << 16);
    w.y = f2bf(a2 * inv16) | (f2bf(a3 * inv16) << 16);
    w.z = f2bf(a4 * inv16) | (f2bf(a5 * inv16) << 16);
    w.w = f2bf(a6 * inv16) | (f2bf(a7 * inv16) << 16);
    *(uint4*)(xp1h + (size_t)d * 128 + (h << 4)) = w;
  }
}

// ---- P2: dense h=elu(hpre+b1); xp2=h@W2; write segmented 64B xp2 row ------
__global__ __launch_bounds__(256) void k_proj2(
    const unsigned char* __restrict__ xp1h, const float* __restrict__ b1,
    const float* __restrict__ W2, const float* __restrict__ a_src2,
    const float* __restrict__ a_dst2,
    unsigned int* __restrict__ xp2b, float* __restrict__ adst2, int n)
{
  __shared__ float sW[64 * 20];
  for (int i = threadIdx.x; i < 64 * 20; i += 256) sW[i] = W2[i];
  __syncthreads();
  const int node = blockIdx.x * 64 + (threadIdx.x >> 2);
  const int part = threadIdx.x & 3;
  if (node >= n) return;
  const int k0 = part * 16;
  const uint4 u0 = *(const uint4*)(xp1h + (size_t)node * 128 + k0 * 2);
  const uint4 u1 = *(const uint4*)(xp1h + (size_t)node * 128 + k0 * 2 + 16);
  float hv[16];
  {
    const unsigned uu[8] = {u0.x,u0.y,u0.z,u0.w,u1.x,u1.y,u1.z,u1.w};
#pragma unroll
    for (int j = 0; j < 8; ++j) {
      float t0 = __uint_as_float(uu[j] << 16)        + b1[k0 + 2*j];
      float t1 = __uint_as_float(uu[j] & 0xFFFF0000u) + b1[k0 + 2*j + 1];
      hv[2*j]   = t0 > 0.f ? t0 : expm1f(t0);
      hv[2*j+1] = t1 > 0.f ? t1 : expm1f(t1);
    }
  }
  float acc[20];
#pragma unroll
  for (int c = 0; c < 20; ++c) acc[c] = 0.f;
#pragma unroll
  for (int j = 0; j < 16; ++j) {
    const float hj = hv[j];
    const float* wr = sW + (k0 + j) * 20;
#pragma unroll
    for (int c = 0; c < 20; ++c) acc[c] = fmaf(hj, wr[c], acc[c]);
  }
#pragma unroll
  for (int c = 0; c < 20; ++c) {
    acc[c] += __shfl_xor(acc[c], 1);
    acc[c] += __shfl_xor(acc[c], 2);
  }
  float vs = 0.f, vd = 0.f;
#pragma unroll
  for (int c = 0; c < 20; ++c) {
    vs = fmaf(acc[c], a_src2[c], vs);
    vd = fmaf(acc[c], a_dst2[c], vd);
  }
  const int p5 = part * 5;
  uint4 w;
  w.x = f2bf(acc[p5 + 0]) | (f2bf(acc[p5 + 1]) << 16);
  w.y = f2bf(acc[p5 + 2]) | (f2bf(acc[p5 + 3]) << 16);
  w.z = f2bf(acc[p5 + 4]);
  w.w = __float_as_uint(vs);
  *(uint4*)(xp2b + (size_t)node * 16 + part * 4) = w;
  if (part == 0) adst2[node] = vd;
}

// ---- G2: layer-2 gather (16 edges/wave, segment rows) + log_softmax -------
__global__ __launch_bounds__(256) void k_gather2(
    const int* __restrict__ offs, const int* __restrict__ csr,
    const float* __restrict__ adst2,
    const unsigned char* __restrict__ xp2c, const float* __restrict__ b2,
    float* __restrict__ out, int n)
{
  const int wid = threadIdx.x >> 6, ln = threadIdx.x & 63;
  const int eslot = ln >> 2, q = ln & 3;
  const int d = blockIdx.x * 4 + wid;
  if (d >= n) return;
  const int beg = offs[d], end = offs[d + 1];
  const float adT = adst2[d];
  const int qoff = q << 4;
  float a0=0.f,a1=0.f,a2=0.f,a3=0.f,a4=0.f,den=0.f;
#pragma unroll 2
  for (int jb = beg + eslot; jb < end; jb += 16) {
    const int sv = __builtin_nontemporal_load(&csr[jb]);   // src<<6
    const uint4 u = *(const uint4*)(xp2c + (unsigned)sv + qoff);
    const float p = __expf(lrelu(__uint_as_float(u.w) + adT));
    a0 = fmaf(p, __uint_as_float(u.x << 16), a0);
    a1 = fmaf(p, __uint_as_float(u.x & 0xFFFF0000u), a1);
    a2 = fmaf(p, __uint_as_float(u.y << 16), a2);
    a3 = fmaf(p, __uint_as_float(u.y & 0xFFFF0000u), a3);
    a4 = fmaf(p, __uint_as_float(u.z << 16), a4);
    den += p;
  }
#pragma unroll
  for (int off = 4; off < 64; off <<= 1) {
    a0 += __shfl_xor(a0, off); a1 += __shfl_xor(a1, off);
    a2 += __shfl_xor(a2, off); a3 += __shfl_xor(a3, off);
    a4 += __shfl_xor(a4, off);
    den += __shfl_xor(den, off);
  }
  const float inv = 1.f / den;
  const int c5 = q * 5;
  float o[5];
  float mx;
  {
    o[0] = a0 * inv + b2[c5 + 0];
    o[1] = a1 * inv + b2[c5 + 1];
    o[2] = a2 * inv + b2[c5 + 2];
    o[3] = a3 * inv + b2[c5 + 3];
    o[4] = a4 * inv + b2[c5 + 4];
    mx = fmaxf(fmaxf(fmaxf(o[0], o[1]), fmaxf(o[2], o[3])), o[4]);
  }
  mx = fmaxf(mx, __shfl_xor(mx, 1));
  mx = fmaxf(mx, __shfl_xor(mx, 2));
  float ss = __expf(o[0] - mx) + __expf(o[1] - mx) + __expf(o[2] - mx)
           + __expf(o[3] - mx) + __expf(o[4] - mx);
  ss += __shfl_xor(ss, 1);
  ss += __shfl_xor(ss, 2);
  const float lse = mx + __logf(ss);
  if (eslot == 0) {
#pragma unroll
    for (int j = 0; j < 5; ++j)
      out[(size_t)d * 20 + c5 + j] = o[j] - lse;
  }
}

// ---------------------------------------------------------------------------

extern "C" void kernel_launch(void* const* d_in, const int* in_sizes, int n_in,
                              void* d_out, int out_size, void* d_ws, size_t ws_size,
                              hipStream_t stream)
{
  const int*   x_ids  = (const int*)d_in[0];
  const int*   ei     = (const int*)d_in[1];   // [2,E]: [0..E)=src, [E..2E)=dst
  const float* emb    = (const float*)d_in[2];
  const float* W1     = (const float*)d_in[3];
  const float* a_src1 = (const float*)d_in[4];
  const float* a_dst1 = (const float*)d_in[5];
  const float* b1     = (const float*)d_in[6];
  const float* W2     = (const float*)d_in[7];
  const float* a_src2 = (const float*)d_in[8];
  const float* a_dst2 = (const float*)d_in[9];
  const float* b2     = (const float*)d_in[10];
  float* out = (float*)d_out;

  const int n = in_sizes[0];
  const int E = in_sizes[1] / 2;
  const int nb = (n + 255) >> 8;               // buckets of 256 dst ids

  // workspace layout (bytes). xp1f8 aliases buf (build-phase only).
  char* base = (char*)d_ws;
  size_t r0 = (size_t)n * 64;                  // xp1f8: n*64*1 B
  if ((size_t)E * 4 > r0) r0 = (size_t)E * 4;  // buf:  E*4 B
  r0 = (r0 + 255) & ~(size_t)255;
  unsigned char* xp1f8 = (unsigned char*)base;
  int*   buf   = (int*)base;
  float* adst1 = (float*)(base + r0);                    // n*8 f32
  unsigned char* xp1h = (unsigned char*)(adst1 + (size_t)n * 8); // n*128 B
  unsigned int* xp2b = (unsigned int*)(xp1h + (size_t)n * 128);  // n*16 uint
  float* adst2 = (float*)(xp2b + (size_t)n * 16);        // n
  int*   offs   = (int*)(adst2 + (size_t)n);   // n+1
  int*   bhistP = offs + n + 1;                // NHB*256 (all slots written)
  int*   bufOffs= bhistP + NHB * 256;          // nb+1
  int*   tail   = bufOffs + 257;               // 256
  int*   csr    = tail + 256;                  // E+n

  // NOTE: xp1f8 aliases buf. The fused kernel's embed blocks WRITE xp1f8
  // while its coffs blocks READ buf — conflict! Keep them separate: embed
  // writes go to xp1f8 which aliases buf... so give xp1f8 its own region.
  // (buf is dead after the fused kernel; xp1f8 placed after csr instead.)
  unsigned char* xp1f8_real = (unsigned char*)(csr + (size_t)E + n);
  xp1f8 = xp1f8_real;

  k_bhist<<<NHB, 256, 0, stream>>>(ei, bhistP, E);
  k_bscan<<<1, 256, 0, stream>>>(bhistP, bufOffs, tail, nb);
  k_part<<<(E + EPB - 1) / EPB, 256, 0, stream>>>(ei, tail, buf, E);

  {
    const int embBlocks = (n + 31) / 32;
    k_coffs_embed<<<nb + embBlocks, 256, 0, stream>>>(
        buf, bufOffs, offs, csr, nb,
        x_ids, emb, W1, a_dst1, xp1f8, adst1, n);
  }

  k_gather1<<<(n + 3) / 4, 256, 0, stream>>>(
      offs, csr, a_src1, adst1, xp1f8, xp1h, n);

  k_proj2<<<(n + 63) / 64, 256, 0, stream>>>(
      xp1h, b1, W2, a_src2, a_dst2, xp2b, adst2, n);

  k_gather2<<<(n + 3) / 4, 256, 0, stream>>>(
      offs, csr, adst2, (const unsigned char*)xp2b, b2, out, n);
}